// Round 8
// baseline (185.109 us; speedup 1.0000x reference)
//
#include <hip/hip_runtime.h>

// ARMAConv x2 GNN: N=40000, E=640000, F_IN=512, HID=128, NCLS=64
#define F_IN 512
#define HID 128
#define NCLS 64
#define MPAD 40064  // 313 * 128; also 1252 * 32

typedef __bf16 bf16x8 __attribute__((ext_vector_type(8)));
typedef float f32x4 __attribute__((ext_vector_type(4)));

__device__ __forceinline__ float lo16(unsigned u) {
    unsigned x = u << 16;
    float f;
    __builtin_memcpy(&f, &x, 4);
    return f;
}
__device__ __forceinline__ float hi16(unsigned u) {
    unsigned x = u & 0xffff0000u;
    float f;
    __builtin_memcpy(&f, &x, 4);
    return f;
}

// ---------------- degree count ----------------
__global__ __launch_bounds__(256) void count_kernel(const int* __restrict__ dst,
                                                    int* __restrict__ cnt, int E) {
    int i = blockIdx.x * 256 + threadIdx.x;
    if (i < E) atomicAdd(&cnt[dst[i]], 1);
}

// ---------------- scan stage 1 (+ fused dinv) ----------------
__global__ __launch_bounds__(1024) void scan1_kernel(const int* __restrict__ cnt,
                                                     int* __restrict__ rowptr,
                                                     int* __restrict__ bsum,
                                                     float* __restrict__ dinv, int n) {
    __shared__ int s[1024];
    int tid = threadIdx.x;
    int i = blockIdx.x * 1024 + tid;
    int v = (i < n) ? cnt[i] : 0;
    if (i < n) dinv[i] = v > 0 ? rsqrtf((float)v) : 0.f;
    s[tid] = v;
    __syncthreads();
    for (int off = 1; off < 1024; off <<= 1) {
        int t = (tid >= off) ? s[tid - off] : 0;
        __syncthreads();
        s[tid] += t;
        __syncthreads();
    }
    if (i < n) rowptr[i] = s[tid] - v;  // exclusive within block
    if (tid == 1023) bsum[blockIdx.x] = s[1023];
}

// ---------------- scan stage 2+3 fused ----------------
__global__ __launch_bounds__(1024) void scan23_kernel(int* __restrict__ rowptr,
                                                      const int* __restrict__ bsum, int n) {
    __shared__ int off_s;
    if (threadIdx.x == 0) {
        int run = 0;
        for (int b = 0; b < (int)blockIdx.x; ++b) run += bsum[b];
        off_s = run;
    }
    __syncthreads();
    int i = blockIdx.x * 1024 + threadIdx.x;
    if (i < n) rowptr[i] += off_s;
}

// ---------------- CSR fill: bump rowptr in place (becomes end-offsets) ----------------
__global__ __launch_bounds__(256) void fill_kernel(const int* __restrict__ src,
                                                   const int* __restrict__ dst,
                                                   int* __restrict__ rowptr,
                                                   const float* __restrict__ dinv,
                                                   uint2* __restrict__ epk, int E) {
    int e = blockIdx.x * 256 + threadIdx.x;
    if (e < E) {
        int s = src[e];
        int d = dst[e];
        int pos = atomicAdd(&rowptr[d], 1);
        float nr = dinv[s] * dinv[d];
        unsigned nu;
        __builtin_memcpy(&nu, &nr, 4);
        epk[pos] = make_uint2((unsigned)s, nu);
    }
}

// ---------------- weight prep (both layers in one launch) ----------------
__global__ __launch_bounds__(256) void prep_w_kernel(const float* __restrict__ W1i,
                                                     const float* __restrict__ W1r,
                                                     const float* __restrict__ W2i,
                                                     const float* __restrict__ W2r,
                                                     __bf16* __restrict__ W1t,
                                                     __bf16* __restrict__ W2t) {
    int n = blockIdx.x;
    if (n < 256) {
        const float* Wsrc = (n < HID) ? W1i : W1r;
        int c = (n < HID) ? n : n - HID;
        for (int k = threadIdx.x; k < F_IN; k += 256)
            W1t[(long)n * F_IN + k] = (__bf16)Wsrc[(long)k * HID + c];
    } else {
        int m = n - 256;
        const float* Wsrc = (m < NCLS) ? W2i : W2r;
        int c = (m < NCLS) ? m : m - NCLS;
        for (int k = threadIdx.x; k < HID; k += 256)
            W2t[(long)m * HID + k] = (__bf16)Wsrc[(long)k * NCLS + c];
    }
}

// ---------------- GEMM1: H[Mp][256] = bf16(A_f32[M][512]) @ Bt[256][512]^T ----------------
// 32x256 tile, 512 thr (8 waves: 2M x 4N), BK=64, grid 1252.
// A: per-lane DIRECT global->reg (MFMA A-frag: row=lane&15, k-octet=lane>>4),
//    parity-double-buffered across K-steps (full HBM latency hidden under compute).
// B: LDS double-buffer 2x32KB via global_load_lds (pre-swizzled source, linear dest),
//    counted vmcnt(8) so next step's 8 loads stay in flight across both barriers (T4).
__global__ __launch_bounds__(512, 4) void gemm1_kernel(const float* __restrict__ A,
                                                       const __bf16* __restrict__ Bt,
                                                       const float* __restrict__ bias,
                                                       __bf16* __restrict__ H, int M) {
    __shared__ char smem[65536];  // two 32KB B buffers
    const int tid = threadIdx.x;
    const int w = tid >> 6, l = tid & 63;
    const int wm = w >> 2, wn = w & 3;   // 2M x 4N wave grid
    const int lr = l & 15, lg = l >> 4;
    const long m0 = (long)blockIdx.x * 32;

    f32x4 acc[4] = {};

    // A source: lane covers row m0+wm*16+lr, k-octet lg*8 (+kt*64 +kk*32)
    long arow = m0 + wm * 16 + lr;
    if (arow >= M) arow = M - 1;  // tail clamp: rows >= M never consumed downstream
    const float* aptr = A + arow * F_IN + lg * 8;

    // B staging: 4 x 16B per thread per step; pre-swizzled global source, linear LDS dest
    const char* gsrc[4];
    int ldso[4];
#pragma unroll
    for (int j = 0; j < 4; ++j) {
        int q = (tid + j * 512) * 16;  // byte in [0, 32768)
        int c = q >> 7, off = q & 127;
        gsrc[j] = (const char*)Bt + (long)c * 1024 + (off ^ ((c & 7) << 4));
        ldso[j] = (w * 64 + j * 512) * 16;  // wave-uniform base (HW adds lane*16)
    }

    // B read offsets (swizzled)
    int b_off[2][4];
#pragma unroll
    for (int fn = 0; fn < 4; ++fn) {
        int c = wn * 64 + fn * 16 + lr, s = (c & 7) << 4;
#pragma unroll
        for (int kk = 0; kk < 2; ++kk)
            b_off[kk][fn] = c * 128 + ((kk * 64 + lg * 16) ^ s);
    }

#define ISSUE_B(t, buf)                                                                     \
    {                                                                                       \
        _Pragma("unroll") for (int j = 0; j < 4; ++j) {                                     \
            __builtin_amdgcn_global_load_lds(                                               \
                (const __attribute__((address_space(1))) unsigned*)(const void*)(gsrc[j] +  \
                                                                                 (t)*128),  \
                (__attribute__((address_space(3))) unsigned*)(void*)(smem + (buf)*32768 +   \
                                                                     ldso[j]),              \
                16, 0, 0);                                                                  \
        }                                                                                   \
    }

    float4 ar[2][4];  // A reg double-buffer (all indices static after unroll)
#pragma unroll
    for (int i = 0; i < 4; ++i)
        ar[0][i] = *reinterpret_cast<const float4*>(aptr + ((i >> 1) * 32) + ((i & 1) * 4));
    ISSUE_B(0, 0);

#pragma unroll
    for (int kt = 0; kt < 8; ++kt) {
        __builtin_amdgcn_s_barrier();  // buf[(kt+1)&1] readers (iter kt-1) done
        if (kt < 7) {
            ISSUE_B(kt + 1, (kt + 1) & 1);
#pragma unroll
            for (int i = 0; i < 4; ++i)
                ar[(kt + 1) & 1][i] = *reinterpret_cast<const float4*>(
                    aptr + (kt + 1) * 64 + ((i >> 1) * 32) + ((i & 1) * 4));
            asm volatile("s_waitcnt vmcnt(8)" ::: "memory");  // B[kt],A[kt] landed; new 8 fly
        } else {
            asm volatile("s_waitcnt vmcnt(0)" ::: "memory");
        }
        __builtin_amdgcn_s_barrier();  // B[kt] visible to all waves
        __builtin_amdgcn_sched_barrier(0);

        // cvt A[kt] frags
        bf16x8 a0, a1;
        {
            float4 r0 = ar[kt & 1][0], r1 = ar[kt & 1][1];
            float4 r2 = ar[kt & 1][2], r3 = ar[kt & 1][3];
            a0[0] = (__bf16)r0.x; a0[1] = (__bf16)r0.y; a0[2] = (__bf16)r0.z; a0[3] = (__bf16)r0.w;
            a0[4] = (__bf16)r1.x; a0[5] = (__bf16)r1.y; a0[6] = (__bf16)r1.z; a0[7] = (__bf16)r1.w;
            a1[0] = (__bf16)r2.x; a1[1] = (__bf16)r2.y; a1[2] = (__bf16)r2.z; a1[3] = (__bf16)r2.w;
            a1[4] = (__bf16)r3.x; a1[5] = (__bf16)r3.y; a1[6] = (__bf16)r3.z; a1[7] = (__bf16)r3.w;
        }
        const char* bb = smem + (kt & 1) * 32768;
#pragma unroll
        for (int kk = 0; kk < 2; ++kk) {
            bf16x8 va = kk ? a1 : a0;
#pragma unroll
            for (int fn = 0; fn < 4; ++fn) {
                bf16x8 vb = *reinterpret_cast<const bf16x8*>(bb + b_off[kk][fn]);
                acc[fn] = __builtin_amdgcn_mfma_f32_16x16x32_bf16(va, vb, acc[fn], 0, 0, 0);
            }
        }
        __builtin_amdgcn_sched_barrier(0);  // keep ds_reads inside their phase
    }
#undef ISSUE_B

    // epilogue: C/D col=lane&15, row=(lane>>4)*4+j
#pragma unroll
    for (int fn = 0; fn < 4; ++fn) {
        int col = wn * 64 + fn * 16 + lr;
        float bvv = (col >= HID) ? bias[col - HID] : 0.f;
        long row = m0 + wm * 16 + lg * 4;
#pragma unroll
        for (int j2 = 0; j2 < 4; ++j2)
            H[(row + j2) * 256 + col] = (__bf16)(acc[fn][j2] + bvv);
    }
}

// ---------------- GEMM2 (bf16 A): H[Mp][128] = A[Mp][128] @ Bt[128][128]^T ----------------
template <int NT, int NH>
__global__ __launch_bounds__(256) void gemm_mfma(const __bf16* __restrict__ A,
                                                 const __bf16* __restrict__ Bt,
                                                 const float* __restrict__ bias,
                                                 __bf16* __restrict__ H, int K) {
    __shared__ char smem[24576];
    const int tid = threadIdx.x;
    const int w = tid >> 6, l = tid & 63;
    const int lr = l & 15, lg = l >> 4;
    const long m0 = (long)blockIdx.x * 128;
    const int n0 = blockIdx.y * 64;
    const long Kb = (long)K * 2;

    f32x4 acc[2][4] = {};

    int a_off[2][2], b_off[2][4];
#pragma unroll
    for (int fm = 0; fm < 2; ++fm) {
        int r = w * 32 + fm * 16 + lr;
        int s = (r & 7) << 4;
#pragma unroll
        for (int kk = 0; kk < 2; ++kk)
            a_off[fm][kk] = r * 128 + ((kk * 64 + lg * 16) ^ s);
    }
#pragma unroll
    for (int fn = 0; fn < 4; ++fn) {
        int c = fn * 16 + lr;
        int s = (c & 7) << 4;
#pragma unroll
        for (int kk = 0; kk < 2; ++kk)
            b_off[kk][fn] = 16384 + c * 128 + ((kk * 64 + lg * 16) ^ s);
    }

    const char* gsrc[6];
    char* ldst[6];
#pragma unroll
    for (int j = 0; j < 6; ++j) {
        int p = (w * 6 + j) * 1024 + l * 16;
        ldst[j] = smem + (w * 6 + j) * 1024;
        if (p < 16384) {
            int row = p >> 7;
            int loff = (p & 127) ^ ((row & 7) << 4);
            gsrc[j] = (const char*)A + (m0 + row) * Kb + loff;
        } else {
            int q = p - 16384;
            int c = q >> 7;
            int loff = (q & 127) ^ ((c & 7) << 4);
            gsrc[j] = (const char*)Bt + (long)(n0 + c) * Kb + loff;
        }
    }

    const int nk = K >> 6;
    for (int kt = 0; kt < nk; ++kt) {
#pragma unroll
        for (int j = 0; j < 6; ++j) {
            __builtin_amdgcn_global_load_lds(
                (const __attribute__((address_space(1))) unsigned*)(const void*)(gsrc[j] + (long)kt * 128),
                (__attribute__((address_space(3))) unsigned*)(void*)ldst[j], 16, 0, 0);
        }
        __syncthreads();
#pragma unroll
        for (int kk = 0; kk < 2; ++kk) {
            bf16x8 av[2], bv[4];
#pragma unroll
            for (int fm = 0; fm < 2; ++fm)
                av[fm] = *reinterpret_cast<const bf16x8*>(smem + a_off[fm][kk]);
#pragma unroll
            for (int fn = 0; fn < 4; ++fn)
                bv[fn] = *reinterpret_cast<const bf16x8*>(smem + b_off[kk][fn]);
#pragma unroll
            for (int fm = 0; fm < 2; ++fm)
#pragma unroll
                for (int fn = 0; fn < 4; ++fn)
                    acc[fm][fn] = __builtin_amdgcn_mfma_f32_16x16x32_bf16(
                        av[fm], bv[fn], acc[fm][fn], 0, 0, 0);
        }
        __syncthreads();
    }

#pragma unroll
    for (int fn = 0; fn < 4; ++fn) {
        int col = n0 + fn * 16 + lr;
        float bvv = (col >= NH) ? bias[col - NH] : 0.f;
#pragma unroll
        for (int fm = 0; fm < 2; ++fm) {
            long row = m0 + w * 32 + fm * 16 + lg * 4;
#pragma unroll
            for (int j2 = 0; j2 < 4; ++j2)
                H[(row + j2) * NT + col] = (__bf16)(acc[fm][fn][j2] + bvv);
        }
    }
}

// ---------------- gather F=128: quarter-wave, 16 edges in flight per wave ----------------
__global__ __launch_bounds__(256) void gather128_kernel(const int* __restrict__ rowptr,
                                                        const int* __restrict__ cnt,
                                                        const uint2* __restrict__ epk,
                                                        const unsigned short* __restrict__ Hb,
                                                        __bf16* __restrict__ outb, int n) {
    int wid = (blockIdx.x * 256 + threadIdx.x) >> 6;
    int l = threadIdx.x & 63;
    if (wid >= n) return;
    const int len = cnt[wid];
    const int s0 = rowptr[wid] - len;  // rowptr holds end-offsets after fill
    const int li = l & 15, q = l >> 4;

    int sv = 0;
    float nv = 0.f;
    if (l < len) {
        uint2 p = epk[s0 + l];
        sv = (int)p.x;
        nv = __uint_as_float(p.y);
    }
    const int m = len < 64 ? len : 64;
    const int T = (m + 3) >> 2;

    float a[8] = {};
#pragma unroll 4
    for (int t = 0; t < T; ++t) {
        int e = 4 * t + q;
        int s = __shfl(sv, e);
        float nr = __shfl(nv, e);
        uint4 v = *reinterpret_cast<const uint4*>(Hb + (size_t)s * 256 + 8 * li);
        a[0] = fmaf(nr, lo16(v.x), a[0]);
        a[1] = fmaf(nr, hi16(v.x), a[1]);
        a[2] = fmaf(nr, lo16(v.y), a[2]);
        a[3] = fmaf(nr, hi16(v.y), a[3]);
        a[4] = fmaf(nr, lo16(v.z), a[4]);
        a[5] = fmaf(nr, hi16(v.z), a[5]);
        a[6] = fmaf(nr, lo16(v.w), a[6]);
        a[7] = fmaf(nr, hi16(v.w), a[7]);
    }
    for (int k = 64; k < len; ++k) {  // tail: essentially never (Poisson(16))
        if (q == 0) {
            uint2 p = epk[s0 + k];
            int s = (int)p.x;
            float nr = __uint_as_float(p.y);
            uint4 v = *reinterpret_cast<const uint4*>(Hb + (size_t)s * 256 + 8 * li);
            a[0] = fmaf(nr, lo16(v.x), a[0]);
            a[1] = fmaf(nr, hi16(v.x), a[1]);
            a[2] = fmaf(nr, lo16(v.y), a[2]);
            a[3] = fmaf(nr, hi16(v.y), a[3]);
            a[4] = fmaf(nr, lo16(v.z), a[4]);
            a[5] = fmaf(nr, hi16(v.z), a[5]);
            a[6] = fmaf(nr, lo16(v.w), a[6]);
            a[7] = fmaf(nr, hi16(v.w), a[7]);
        }
    }
#pragma unroll
    for (int i = 0; i < 8; ++i) {
        a[i] += __shfl_xor(a[i], 16);
        a[i] += __shfl_xor(a[i], 32);
    }
    if (l < 16) {
        uint4 rv = *reinterpret_cast<const uint4*>(Hb + (size_t)wid * 256 + 128 + 8 * l);
        float r[8] = {lo16(rv.x), hi16(rv.x), lo16(rv.y), hi16(rv.y),
                      lo16(rv.z), hi16(rv.z), lo16(rv.w), hi16(rv.w)};
        union { uint4 v; __bf16 b[8]; } o;
#pragma unroll
        for (int i = 0; i < 8; ++i) o.b[i] = (__bf16)fmaxf(a[i] + r[i], 0.f);
        *reinterpret_cast<uint4*>(outb + (size_t)wid * 128 + 8 * l) = o.v;
    }
}

// ---------------- gather F=64: quarter-wave, fp32 out ----------------
__global__ __launch_bounds__(256) void gather64_kernel(const int* __restrict__ rowptr,
                                                       const int* __restrict__ cnt,
                                                       const uint2* __restrict__ epk,
                                                       const unsigned short* __restrict__ Hb,
                                                       float* __restrict__ out, int n) {
    int wid = (blockIdx.x * 256 + threadIdx.x) >> 6;
    int l = threadIdx.x & 63;
    if (wid >= n) return;
    const int len = cnt[wid];
    const int s0 = rowptr[wid] - len;
    const int li = l & 15, q = l >> 4;

    int sv = 0;
    float nv = 0.f;
    if (l < len) {
        uint2 p = epk[s0 + l];
        sv = (int)p.x;
        nv = __uint_as_float(p.y);
    }
    const int m = len < 64 ? len : 64;
    const int T = (m + 3) >> 2;

    float a[4] = {};
#pragma unroll 4
    for (int t = 0; t < T; ++t) {
        int e = 4 * t + q;
        int s = __shfl(sv, e);
        float nr = __shfl(nv, e);
        uint2 v = *reinterpret_cast<const uint2*>(Hb + (size_t)s * 128 + 4 * li);
        a[0] = fmaf(nr, lo16(v.x), a[0]);
        a[1] = fmaf(nr, hi16(v.x), a[1]);
        a[2] = fmaf(nr, lo16(v.y), a[2]);
        a[3] = fmaf(nr, hi16(v.y), a[3]);
    }
    for (int k = 64; k < len; ++k) {
        if (q == 0) {
            uint2 p = epk[s0 + k];
            int s = (int)p.x;
            float nr = __uint_as_float(p.y);
            uint2 v = *reinterpret_cast<const uint2*>(Hb + (size_t)s * 128 + 4 * li);
            a[0] = fmaf(nr, lo16(v.x), a[0]);
            a[1] = fmaf(nr, hi16(v.x), a[1]);
            a[2] = fmaf(nr, lo16(v.y), a[2]);
            a[3] = fmaf(nr, hi16(v.y), a[3]);
        }
    }
#pragma unroll
    for (int i = 0; i < 4; ++i) {
        a[i] += __shfl_xor(a[i], 16);
        a[i] += __shfl_xor(a[i], 32);
    }
    if (l < 16) {
        uint2 rv = *reinterpret_cast<const uint2*>(Hb + (size_t)wid * 128 + 64 + 4 * l);
        float4 o;
        o.x = fmaxf(a[0] + lo16(rv.x), 0.f);
        o.y = fmaxf(a[1] + hi16(rv.x), 0.f);
        o.z = fmaxf(a[2] + lo16(rv.y), 0.f);
        o.w = fmaxf(a[3] + hi16(rv.y), 0.f);
        *reinterpret_cast<float4*>(out + (size_t)wid * 64 + 4 * l) = o;
    }
}

extern "C" void kernel_launch(void* const* d_in, const int* in_sizes, int n_in,
                              void* d_out, int out_size, void* d_ws, size_t ws_size,
                              hipStream_t stream) {
    const float* x   = (const float*)d_in[0];
    const float* W1i = (const float*)d_in[1];
    const float* W1r = (const float*)d_in[2];
    const float* b1  = (const float*)d_in[3];
    const float* W2i = (const float*)d_in[4];
    const float* W2r = (const float*)d_in[5];
    const float* b2  = (const float*)d_in[6];
    const int*   ei  = (const int*)d_in[7];

    const int E = in_sizes[7] / 2;
    const int M = in_sizes[0] / F_IN;  // 40000
    const int* src = ei;
    const int* dst = ei + E;

    char* w = (char*)d_ws;
    int*    cnt    = (int*)w;            w += 40960 * 4;
    int*    rowptr = (int*)w;            w += 40960 * 4;
    float*  dinv   = (float*)w;          w += 40960 * 4;
    int*    bsum   = (int*)w;            w += 4096;
    uint2*  epk    = (uint2*)w;          w += (size_t)E * 8;
    __bf16* W1t    = (__bf16*)w;         w += 256 * 512 * 2;
    __bf16* W2t    = (__bf16*)w;         w += 128 * 128 * 2;
    __bf16* H1b    = (__bf16*)w;         w += (size_t)MPAD * 256 * 2;  // 20.5MB
    __bf16* out1b  = (__bf16*)w;         w += (size_t)MPAD * 128 * 2;  // 10.25MB
    __bf16* H2b    = (__bf16*)w;         w += (size_t)MPAD * 128 * 2;  // 10.25MB
    float*  outp   = (float*)d_out;

    const int nb = (M + 1023) / 1024;

    // ---- CSR build ----
    hipMemsetAsync(cnt, 0, (size_t)M * sizeof(int), stream);
    count_kernel<<<(E + 255) / 256, 256, 0, stream>>>(dst, cnt, E);
    scan1_kernel<<<nb, 1024, 0, stream>>>(cnt, rowptr, bsum, dinv, M);
    scan23_kernel<<<nb, 1024, 0, stream>>>(rowptr, bsum, M);
    fill_kernel<<<(E + 255) / 256, 256, 0, stream>>>(src, dst, rowptr, dinv, epk, E);

    // ---- weight prep (both layers) ----
    prep_w_kernel<<<384, 256, 0, stream>>>(W1i, W1r, W2i, W2r, W1t, W2t);

    // ---- layer 1 (cast fused into GEMM, A direct-from-global) ----
    gemm1_kernel<<<MPAD / 32, 512, 0, stream>>>(x, W1t, b1, H1b, M);
    gather128_kernel<<<(M * 64 + 255) / 256, 256, 0, stream>>>(
        rowptr, cnt, epk, (const unsigned short*)H1b, out1b, M);

    // ---- layer 2 ----
    gemm_mfma<128, 64><<<dim3(MPAD / 128, 2), 256, 0, stream>>>(out1b, W2t, b2, H2b, HID);
    gather64_kernel<<<(M * 64 + 255) / 256, 256, 0, stream>>>(
        rowptr, cnt, epk, (const unsigned short*)H2b, outp, M);
}

// Round 10
// 159.992 us; speedup vs baseline: 1.1570x; 1.1570x over previous
//
#include <hip/hip_runtime.h>

// ARMAConv x2 GNN: N=40000, E=640000, F_IN=512, HID=128, NCLS=64
#define F_IN 512
#define HID 128
#define NCLS 64
#define MPAD 40064  // 313 * 128; 626 * 64

typedef __bf16 bf16x8 __attribute__((ext_vector_type(8)));
typedef float f32x4 __attribute__((ext_vector_type(4)));

__device__ __forceinline__ float lo16(unsigned u) {
    unsigned x = u << 16;
    float f;
    __builtin_memcpy(&f, &x, 4);
    return f;
}
__device__ __forceinline__ float hi16(unsigned u) {
    unsigned x = u & 0xffff0000u;
    float f;
    __builtin_memcpy(&f, &x, 4);
    return f;
}

// ---------------- degree count ----------------
__global__ __launch_bounds__(256) void count_kernel(const int* __restrict__ dst,
                                                    int* __restrict__ cnt, int E) {
    int i = blockIdx.x * 256 + threadIdx.x;
    if (i < E) atomicAdd(&cnt[dst[i]], 1);
}

// ---------------- scan stage 1 (+ fused dinv) ----------------
__global__ __launch_bounds__(1024) void scan1_kernel(const int* __restrict__ cnt,
                                                     int* __restrict__ rowptr,
                                                     int* __restrict__ bsum,
                                                     float* __restrict__ dinv, int n) {
    __shared__ int s[1024];
    int tid = threadIdx.x;
    int i = blockIdx.x * 1024 + tid;
    int v = (i < n) ? cnt[i] : 0;
    if (i < n) dinv[i] = v > 0 ? rsqrtf((float)v) : 0.f;
    s[tid] = v;
    __syncthreads();
    for (int off = 1; off < 1024; off <<= 1) {
        int t = (tid >= off) ? s[tid - off] : 0;
        __syncthreads();
        s[tid] += t;
        __syncthreads();
    }
    if (i < n) rowptr[i] = s[tid] - v;  // exclusive within block
    if (tid == 1023) bsum[blockIdx.x] = s[1023];
}

// ---------------- scan stage 2+3 fused ----------------
__global__ __launch_bounds__(1024) void scan23_kernel(int* __restrict__ rowptr,
                                                      const int* __restrict__ bsum, int n) {
    __shared__ int off_s;
    if (threadIdx.x == 0) {
        int run = 0;
        for (int b = 0; b < (int)blockIdx.x; ++b) run += bsum[b];
        off_s = run;
    }
    __syncthreads();
    int i = blockIdx.x * 1024 + threadIdx.x;
    if (i < n) rowptr[i] += off_s;
}

// ---------------- CSR fill: bump rowptr in place (becomes end-offsets) ----------------
__global__ __launch_bounds__(256) void fill_kernel(const int* __restrict__ src,
                                                   const int* __restrict__ dst,
                                                   int* __restrict__ rowptr,
                                                   const float* __restrict__ dinv,
                                                   uint2* __restrict__ epk, int E) {
    int e = blockIdx.x * 256 + threadIdx.x;
    if (e < E) {
        int s = src[e];
        int d = dst[e];
        int pos = atomicAdd(&rowptr[d], 1);
        float nr = dinv[s] * dinv[d];
        unsigned nu;
        __builtin_memcpy(&nu, &nr, 4);
        epk[pos] = make_uint2((unsigned)s, nu);
    }
}

// ---------------- weight prep (both layers in one launch) ----------------
__global__ __launch_bounds__(256) void prep_w_kernel(const float* __restrict__ W1i,
                                                     const float* __restrict__ W1r,
                                                     const float* __restrict__ W2i,
                                                     const float* __restrict__ W2r,
                                                     __bf16* __restrict__ W1t,
                                                     __bf16* __restrict__ W2t) {
    int n = blockIdx.x;
    if (n < 256) {
        const float* Wsrc = (n < HID) ? W1i : W1r;
        int c = (n < HID) ? n : n - HID;
        for (int k = threadIdx.x; k < F_IN; k += 256)
            W1t[(long)n * F_IN + k] = (__bf16)Wsrc[(long)k * HID + c];
    } else {
        int m = n - 256;
        const float* Wsrc = (m < NCLS) ? W2i : W2r;
        int c = (m < NCLS) ? m : m - NCLS;
        for (int k = threadIdx.x; k < HID; k += 256)
            W2t[(long)m * HID + k] = (__bf16)Wsrc[(long)k * NCLS + c];
    }
}

// ---------------- GEMM1: H[Mp][256] = bf16(A_f32[M][512]) @ Bt[256][512]^T ----------------
// 64x256 tile, 256 thr (4 waves, each wave 16 rows x 256 cols -> acc[16], 32 MFMA/step).
// A: per-lane direct global->reg (MFMA A-frag: row=lr, k-octet=lg*8+kk*32), parity
//    dbuf arA/arB (static names). No A-LDS at all.
// B: LDS dbuf 2x32KB via global_load_lds (pre-swizzled src, linear dest); counted
//    vmcnt(12) per step (8 B + 4 A in flight), raw s_barrier x2, drain only at last step.
__global__ __launch_bounds__(256) void gemm1_kernel(const float* __restrict__ A,
                                                    const __bf16* __restrict__ Bt,
                                                    const float* __restrict__ bias,
                                                    __bf16* __restrict__ H, int M) {
    __shared__ char smem[65536];  // B double buffer: 2 x 32KB
    const int tid = threadIdx.x;
    const int w = tid >> 6, l = tid & 63;
    const int lr = l & 15, lg = l >> 4;
    const long m0 = (long)blockIdx.x * 64;

    f32x4 acc[16] = {};

    // A source: row = m0 + w*16 + lr; k = kt*64 + kk*32 + lg*8
    long arow = m0 + w * 16 + lr;
    if (arow >= M) arow = M - 1;  // tail clamp: rows >= M never consumed downstream
    const float* aptr = A + arow * F_IN + lg * 8;

    // B staging: 8 x 16B per thread per step (32KB/step, 256 thr); swizzled source
    const char* gsrc[8];
    int ldso[8];
#pragma unroll
    for (int j = 0; j < 8; ++j) {
        int q = (tid + j * 256) * 16;  // byte in [0,32768)
        int c = q >> 7, off = q & 127;
        gsrc[j] = (const char*)Bt + (long)c * 1024 + (off ^ ((c & 7) << 4));
        ldso[j] = w * 1024 + j * 4096;  // wave-uniform base (HW adds lane*16)
    }

    // B read addressing: col = fn*16 + lr; (col&7)==(lr&7) so swizzle is lane-constant.
    const int bsw = (lr & 7) << 4;
    const int b_off0 = lr * 128 + ((lg * 16) ^ bsw);        // kk=0
    const int b_off1 = lr * 128 + ((64 + lg * 16) ^ bsw);   // kk=1

#define ISSUE_B(t, buf)                                                                   \
    {                                                                                     \
        _Pragma("unroll") for (int j = 0; j < 8; ++j)                                     \
            __builtin_amdgcn_global_load_lds(                                             \
                (const __attribute__((address_space(1))) unsigned*)(const void*)(gsrc[j] + (t) * 128), \
                (__attribute__((address_space(3))) unsigned*)(void*)(smem + (buf) * 32768 + ldso[j]),  \
                16, 0, 0);                                                                \
    }
#define LOAD_A(AR, t)                                                                     \
    {                                                                                     \
        _Pragma("unroll") for (int i = 0; i < 4; ++i)                                     \
            AR[i] = *reinterpret_cast<const float4*>(aptr + (t) * 64 + (i >> 1) * 32 + (i & 1) * 4); \
    }
#define COMPUTE(AR, buf)                                                                  \
    {                                                                                     \
        bf16x8 a0, a1;                                                                    \
        a0[0] = (__bf16)AR[0].x; a0[1] = (__bf16)AR[0].y; a0[2] = (__bf16)AR[0].z;        \
        a0[3] = (__bf16)AR[0].w; a0[4] = (__bf16)AR[1].x; a0[5] = (__bf16)AR[1].y;        \
        a0[6] = (__bf16)AR[1].z; a0[7] = (__bf16)AR[1].w;                                 \
        a1[0] = (__bf16)AR[2].x; a1[1] = (__bf16)AR[2].y; a1[2] = (__bf16)AR[2].z;        \
        a1[3] = (__bf16)AR[2].w; a1[4] = (__bf16)AR[3].x; a1[5] = (__bf16)AR[3].y;        \
        a1[6] = (__bf16)AR[3].z; a1[7] = (__bf16)AR[3].w;                                 \
        const char* bb = smem + (buf) * 32768;                                            \
        _Pragma("unroll") for (int fn = 0; fn < 16; ++fn) {                               \
            bf16x8 vb = *reinterpret_cast<const bf16x8*>(bb + b_off0 + fn * 2048);        \
            acc[fn] = __builtin_amdgcn_mfma_f32_16x16x32_bf16(a0, vb, acc[fn], 0, 0, 0);  \
        }                                                                                 \
        _Pragma("unroll") for (int fn = 0; fn < 16; ++fn) {                               \
            bf16x8 vb = *reinterpret_cast<const bf16x8*>(bb + b_off1 + fn * 2048);        \
            acc[fn] = __builtin_amdgcn_mfma_f32_16x16x32_bf16(a1, vb, acc[fn], 0, 0, 0);  \
        }                                                                                 \
    }
// One K-step: prefetch [kt+1], counted wait for [kt], barrier, compute [kt], barrier.
#define STEP(kt, CUR, NXT, CBUF, NBUF, LAST)                                              \
    {                                                                                     \
        if (!(LAST)) {                                                                    \
            ISSUE_B(kt + 1, NBUF);                                                        \
            LOAD_A(NXT, kt + 1);                                                          \
            asm volatile("s_waitcnt vmcnt(12)" ::: "memory");                             \
        } else {                                                                          \
            asm volatile("s_waitcnt vmcnt(0)" ::: "memory");                              \
        }                                                                                 \
        __builtin_amdgcn_s_barrier();                                                     \
        __builtin_amdgcn_sched_barrier(0);                                                \
        COMPUTE(CUR, CBUF);                                                               \
        if (!(LAST)) {                                                                    \
            __builtin_amdgcn_sched_barrier(0);                                            \
            __builtin_amdgcn_s_barrier();                                                 \
        }                                                                                 \
    }

    float4 arA[4], arB[4];
    ISSUE_B(0, 0);
    LOAD_A(arA, 0);
    STEP(0, arA, arB, 0, 1, false)
    STEP(1, arB, arA, 1, 0, false)
    STEP(2, arA, arB, 0, 1, false)
    STEP(3, arB, arA, 1, 0, false)
    STEP(4, arA, arB, 0, 1, false)
    STEP(5, arB, arA, 1, 0, false)
    STEP(6, arA, arB, 0, 1, false)
    STEP(7, arB, arA, 1, 0, true)
#undef STEP
#undef COMPUTE
#undef LOAD_A
#undef ISSUE_B

    // epilogue: C/D col=lane&15, row=(lane>>4)*4+j
#pragma unroll
    for (int fn = 0; fn < 16; ++fn) {
        int col = fn * 16 + lr;
        float bvv = (col >= HID) ? bias[col - HID] : 0.f;
        long row = m0 + w * 16 + lg * 4;
#pragma unroll
        for (int j2 = 0; j2 < 4; ++j2)
            H[(row + j2) * 256 + col] = (__bf16)(acc[fn][j2] + bvv);
    }
}

// ---------------- GEMM2 (bf16 A): H[Mp][128] = A[Mp][128] @ Bt[128][128]^T ----------------
template <int NT, int NH>
__global__ __launch_bounds__(256) void gemm_mfma(const __bf16* __restrict__ A,
                                                 const __bf16* __restrict__ Bt,
                                                 const float* __restrict__ bias,
                                                 __bf16* __restrict__ H, int K) {
    __shared__ char smem[24576];
    const int tid = threadIdx.x;
    const int w = tid >> 6, l = tid & 63;
    const int lr = l & 15, lg = l >> 4;
    const long m0 = (long)blockIdx.x * 128;
    const int n0 = blockIdx.y * 64;
    const long Kb = (long)K * 2;

    f32x4 acc[2][4] = {};

    int a_off[2][2], b_off[2][4];
#pragma unroll
    for (int fm = 0; fm < 2; ++fm) {
        int r = w * 32 + fm * 16 + lr;
        int s = (r & 7) << 4;
#pragma unroll
        for (int kk = 0; kk < 2; ++kk)
            a_off[fm][kk] = r * 128 + ((kk * 64 + lg * 16) ^ s);
    }
#pragma unroll
    for (int fn = 0; fn < 4; ++fn) {
        int c = fn * 16 + lr;
        int s = (c & 7) << 4;
#pragma unroll
        for (int kk = 0; kk < 2; ++kk)
            b_off[kk][fn] = 16384 + c * 128 + ((kk * 64 + lg * 16) ^ s);
    }

    const char* gsrc[6];
    char* ldst[6];
#pragma unroll
    for (int j = 0; j < 6; ++j) {
        int p = (w * 6 + j) * 1024 + l * 16;
        ldst[j] = smem + (w * 6 + j) * 1024;
        if (p < 16384) {
            int row = p >> 7;
            int loff = (p & 127) ^ ((row & 7) << 4);
            gsrc[j] = (const char*)A + (m0 + row) * Kb + loff;
        } else {
            int q = p - 16384;
            int c = q >> 7;
            int loff = (q & 127) ^ ((c & 7) << 4);
            gsrc[j] = (const char*)Bt + (long)(n0 + c) * Kb + loff;
        }
    }

    const int nk = K >> 6;
    for (int kt = 0; kt < nk; ++kt) {
#pragma unroll
        for (int j = 0; j < 6; ++j) {
            __builtin_amdgcn_global_load_lds(
                (const __attribute__((address_space(1))) unsigned*)(const void*)(gsrc[j] + (long)kt * 128),
                (__attribute__((address_space(3))) unsigned*)(void*)ldst[j], 16, 0, 0);
        }
        __syncthreads();
#pragma unroll
        for (int kk = 0; kk < 2; ++kk) {
            bf16x8 av[2], bv[4];
#pragma unroll
            for (int fm = 0; fm < 2; ++fm)
                av[fm] = *reinterpret_cast<const bf16x8*>(smem + a_off[fm][kk]);
#pragma unroll
            for (int fn = 0; fn < 4; ++fn)
                bv[fn] = *reinterpret_cast<const bf16x8*>(smem + b_off[kk][fn]);
#pragma unroll
            for (int fm = 0; fm < 2; ++fm)
#pragma unroll
                for (int fn = 0; fn < 4; ++fn)
                    acc[fm][fn] = __builtin_amdgcn_mfma_f32_16x16x32_bf16(
                        av[fm], bv[fn], acc[fm][fn], 0, 0, 0);
        }
        __syncthreads();
    }

#pragma unroll
    for (int fn = 0; fn < 4; ++fn) {
        int col = n0 + fn * 16 + lr;
        float bvv = (col >= NH) ? bias[col - NH] : 0.f;
#pragma unroll
        for (int fm = 0; fm < 2; ++fm) {
            long row = m0 + w * 32 + fm * 16 + lg * 4;
#pragma unroll
            for (int j2 = 0; j2 < 4; ++j2)
                H[(row + j2) * NT + col] = (__bf16)(acc[fm][fn][j2] + bvv);
        }
    }
}

// ---------------- gather F=128: quarter-wave, 16 edges in flight per wave ----------------
__global__ __launch_bounds__(256) void gather128_kernel(const int* __restrict__ rowptr,
                                                        const int* __restrict__ cnt,
                                                        const uint2* __restrict__ epk,
                                                        const unsigned short* __restrict__ Hb,
                                                        __bf16* __restrict__ outb, int n) {
    int wid = (blockIdx.x * 256 + threadIdx.x) >> 6;
    int l = threadIdx.x & 63;
    if (wid >= n) return;
    const int len = cnt[wid];
    const int s0 = rowptr[wid] - len;  // rowptr holds end-offsets after fill
    const int li = l & 15, q = l >> 4;

    int sv = 0;
    float nv = 0.f;
    if (l < len) {
        uint2 p = epk[s0 + l];
        sv = (int)p.x;
        nv = __uint_as_float(p.y);
    }
    const int m = len < 64 ? len : 64;
    const int T = (m + 3) >> 2;

    float a[8] = {};
#pragma unroll 4
    for (int t = 0; t < T; ++t) {
        int e = 4 * t + q;
        int s = __shfl(sv, e);
        float nr = __shfl(nv, e);
        uint4 v = *reinterpret_cast<const uint4*>(Hb + (size_t)s * 256 + 8 * li);
        a[0] = fmaf(nr, lo16(v.x), a[0]);
        a[1] = fmaf(nr, hi16(v.x), a[1]);
        a[2] = fmaf(nr, lo16(v.y), a[2]);
        a[3] = fmaf(nr, hi16(v.y), a[3]);
        a[4] = fmaf(nr, lo16(v.z), a[4]);
        a[5] = fmaf(nr, hi16(v.z), a[5]);
        a[6] = fmaf(nr, lo16(v.w), a[6]);
        a[7] = fmaf(nr, hi16(v.w), a[7]);
    }
    for (int k = 64; k < len; ++k) {  // tail: essentially never (Poisson(16))
        if (q == 0) {
            uint2 p = epk[s0 + k];
            int s = (int)p.x;
            float nr = __uint_as_float(p.y);
            uint4 v = *reinterpret_cast<const uint4*>(Hb + (size_t)s * 256 + 8 * li);
            a[0] = fmaf(nr, lo16(v.x), a[0]);
            a[1] = fmaf(nr, hi16(v.x), a[1]);
            a[2] = fmaf(nr, lo16(v.y), a[2]);
            a[3] = fmaf(nr, hi16(v.y), a[3]);
            a[4] = fmaf(nr, lo16(v.z), a[4]);
            a[5] = fmaf(nr, hi16(v.z), a[5]);
            a[6] = fmaf(nr, lo16(v.w), a[6]);
            a[7] = fmaf(nr, hi16(v.w), a[7]);
        }
    }
#pragma unroll
    for (int i = 0; i < 8; ++i) {
        a[i] += __shfl_xor(a[i], 16);
        a[i] += __shfl_xor(a[i], 32);
    }
    if (l < 16) {
        uint4 rv = *reinterpret_cast<const uint4*>(Hb + (size_t)wid * 256 + 128 + 8 * l);
        float r[8] = {lo16(rv.x), hi16(rv.x), lo16(rv.y), hi16(rv.y),
                      lo16(rv.z), hi16(rv.z), lo16(rv.w), hi16(rv.w)};
        union { uint4 v; __bf16 b[8]; } o;
#pragma unroll
        for (int i = 0; i < 8; ++i) o.b[i] = (__bf16)fmaxf(a[i] + r[i], 0.f);
        *reinterpret_cast<uint4*>(outb + (size_t)wid * 128 + 8 * l) = o.v;
    }
}

// ---------------- gather F=64: quarter-wave, fp32 out ----------------
__global__ __launch_bounds__(256) void gather64_kernel(const int* __restrict__ rowptr,
                                                       const int* __restrict__ cnt,
                                                       const uint2* __restrict__ epk,
                                                       const unsigned short* __restrict__ Hb,
                                                       float* __restrict__ out, int n) {
    int wid = (blockIdx.x * 256 + threadIdx.x) >> 6;
    int l = threadIdx.x & 63;
    if (wid >= n) return;
    const int len = cnt[wid];
    const int s0 = rowptr[wid] - len;
    const int li = l & 15, q = l >> 4;

    int sv = 0;
    float nv = 0.f;
    if (l < len) {
        uint2 p = epk[s0 + l];
        sv = (int)p.x;
        nv = __uint_as_float(p.y);
    }
    const int m = len < 64 ? len : 64;
    const int T = (m + 3) >> 2;

    float a[4] = {};
#pragma unroll 4
    for (int t = 0; t < T; ++t) {
        int e = 4 * t + q;
        int s = __shfl(sv, e);
        float nr = __shfl(nv, e);
        uint2 v = *reinterpret_cast<const uint2*>(Hb + (size_t)s * 128 + 4 * li);
        a[0] = fmaf(nr, lo16(v.x), a[0]);
        a[1] = fmaf(nr, hi16(v.x), a[1]);
        a[2] = fmaf(nr, lo16(v.y), a[2]);
        a[3] = fmaf(nr, hi16(v.y), a[3]);
    }
    for (int k = 64; k < len; ++k) {
        if (q == 0) {
            uint2 p = epk[s0 + k];
            int s = (int)p.x;
            float nr = __uint_as_float(p.y);
            uint2 v = *reinterpret_cast<const uint2*>(Hb + (size_t)s * 128 + 4 * li);
            a[0] = fmaf(nr, lo16(v.x), a[0]);
            a[1] = fmaf(nr, hi16(v.x), a[1]);
            a[2] = fmaf(nr, lo16(v.y), a[2]);
            a[3] = fmaf(nr, hi16(v.y), a[3]);
        }
    }
#pragma unroll
    for (int i = 0; i < 4; ++i) {
        a[i] += __shfl_xor(a[i], 16);
        a[i] += __shfl_xor(a[i], 32);
    }
    if (l < 16) {
        uint2 rv = *reinterpret_cast<const uint2*>(Hb + (size_t)wid * 128 + 64 + 4 * l);
        float4 o;
        o.x = fmaxf(a[0] + lo16(rv.x), 0.f);
        o.y = fmaxf(a[1] + hi16(rv.x), 0.f);
        o.z = fmaxf(a[2] + lo16(rv.y), 0.f);
        o.w = fmaxf(a[3] + hi16(rv.y), 0.f);
        *reinterpret_cast<float4*>(out + (size_t)wid * 64 + 4 * l) = o;
    }
}

extern "C" void kernel_launch(void* const* d_in, const int* in_sizes, int n_in,
                              void* d_out, int out_size, void* d_ws, size_t ws_size,
                              hipStream_t stream) {
    const float* x   = (const float*)d_in[0];
    const float* W1i = (const float*)d_in[1];
    const float* W1r = (const float*)d_in[2];
    const float* b1  = (const float*)d_in[3];
    const float* W2i = (const float*)d_in[4];
    const float* W2r = (const float*)d_in[5];
    const float* b2  = (const float*)d_in[6];
    const int*   ei  = (const int*)d_in[7];

    const int E = in_sizes[7] / 2;
    const int M = in_sizes[0] / F_IN;  // 40000
    const int* src = ei;
    const int* dst = ei + E;

    char* w = (char*)d_ws;
    int*    cnt    = (int*)w;            w += 40960 * 4;
    int*    rowptr = (int*)w;            w += 40960 * 4;
    float*  dinv   = (float*)w;          w += 40960 * 4;
    int*    bsum   = (int*)w;            w += 4096;
    uint2*  epk    = (uint2*)w;          w += (size_t)E * 8;
    __bf16* W1t    = (__bf16*)w;         w += 256 * 512 * 2;
    __bf16* W2t    = (__bf16*)w;         w += 128 * 128 * 2;
    __bf16* H1b    = (__bf16*)w;         w += (size_t)MPAD * 256 * 2;  // 20.5MB
    __bf16* out1b  = (__bf16*)w;         w += (size_t)MPAD * 128 * 2;  // 10.25MB
    __bf16* H2b    = (__bf16*)w;         w += (size_t)MPAD * 128 * 2;  // 10.25MB
    float*  outp   = (float*)d_out;

    const int nb = (M + 1023) / 1024;

    // ---- CSR build ----
    hipMemsetAsync(cnt, 0, (size_t)M * sizeof(int), stream);
    count_kernel<<<(E + 255) / 256, 256, 0, stream>>>(dst, cnt, E);
    scan1_kernel<<<nb, 1024, 0, stream>>>(cnt, rowptr, bsum, dinv, M);
    scan23_kernel<<<nb, 1024, 0, stream>>>(rowptr, bsum, M);
    fill_kernel<<<(E + 255) / 256, 256, 0, stream>>>(src, dst, rowptr, dinv, epk, E);

    // ---- weight prep (both layers) ----
    prep_w_kernel<<<384, 256, 0, stream>>>(W1i, W1r, W2i, W2r, W1t, W2t);

    // ---- layer 1 (cast fused into GEMM, A direct-from-global, B counted-vmcnt dbuf) ----
    gemm1_kernel<<<MPAD / 64, 256, 0, stream>>>(x, W1t, b1, H1b, M);
    gather128_kernel<<<(M * 64 + 255) / 256, 256, 0, stream>>>(
        rowptr, cnt, epk, (const unsigned short*)H1b, out1b, M);

    // ---- layer 2 ----
    gemm_mfma<128, 64><<<dim3(MPAD / 128, 2), 256, 0, stream>>>(out1b, W2t, b2, H2b, HID);
    gather64_kernel<<<(M * 64 + 255) / 256, 256, 0, stream>>>(
        rowptr, cnt, epk, (const unsigned short*)H2b, outp, M);
}